// Round 6
// baseline (176.512 us; speedup 1.0000x reference)
//
#include <hip/hip_runtime.h>

// SSIM (skimage default): 7x7 uniform filter, valid crop (pad=3), sample cov.
// Images: 4096x4096 fp32, output region 4090x4090, result = mean(S) scalar.
//
// R6 = R4 skeleton (proven: 74.5us, VGPR 72, zero spill) + two changes:
//  1. Depth-1 row prefetch: each guarded iteration consumes pixels prefetched
//     last iteration and issues next row's 8 float2 loads before computing.
//     R4's stall profile (VALU 54%, HBM 11%) = exposed per-row load latency;
//     guards (load-bearing vs spill, see R1/R2) also block compiler hoisting,
//     so the pipeline must be explicit. +16 VGPR for prefetch regs.
//  2. Single-rcp epilogue (from R5, VALU-neutral, absmax 0.0):
//     n0/d0+n1/d1 = (n0*d1+n1*d0)*rcp(d0*d1).
// Reverted from R5 (107us regression, stall +32us at equal VALU issue):
// ROWS back to 10 (grid 8x409=3272; more blocks = more overlap), loads back
// to float2 (aligned(8) float4 split/line-cross raised FETCH 82->92MB).
// Note: ring[7][10] lives in AGPRs (VGPR_Count 72 < 80 live floats) — free
// capacity, but ~20 v_accvgpr ops/row counted as VALU.
// Falsifier: VGPR>110 or WRITE_SIZE>10MB -> prefetch spilled, revert it.

#define W_IMG   4096
#define H_IMG   4096
#define OW      4090
#define OH      4090
#define ROWS    10            // output rows per block strip; divides 4090
#define NTHR    256           // threads per block
#define CPB     512           // output columns per block (2 per thread)

__device__ __forceinline__ void load8(const float* __restrict__ p, float o[8])
{
    // 8 consecutive floats, 8B-aligned (c0 even): 4x global_load_dwordx2
    float2 a0 = *(const float2*)(p + 0);
    float2 a1 = *(const float2*)(p + 2);
    float2 a2 = *(const float2*)(p + 4);
    float2 a3 = *(const float2*)(p + 6);
    o[0]=a0.x; o[1]=a0.y; o[2]=a1.x; o[3]=a1.y;
    o[4]=a2.x; o[5]=a2.y; o[6]=a3.x; o[7]=a3.y;
}

__device__ __forceinline__ void hsums_reg(const float o[8], const float t[8],
                                          float h[10])
{
    float so  = ((o[0]+o[1])+(o[2]+o[3])) + ((o[4]+o[5])+o[6]);
    float st  = ((t[0]+t[1])+(t[2]+t[3])) + ((t[4]+t[5])+t[6]);
    float soo = fmaf(o[6],o[6], fmaf(o[5],o[5], fmaf(o[4],o[4], fmaf(o[3],o[3], fmaf(o[2],o[2], fmaf(o[1],o[1], o[0]*o[0]))))));
    float stt = fmaf(t[6],t[6], fmaf(t[5],t[5], fmaf(t[4],t[4], fmaf(t[3],t[3], fmaf(t[2],t[2], fmaf(t[1],t[1], t[0]*t[0]))))));
    float sot = fmaf(o[6],t[6], fmaf(o[5],t[5], fmaf(o[4],t[4], fmaf(o[3],t[3], fmaf(o[2],t[2], fmaf(o[1],t[1], o[0]*t[0]))))));

    h[0] = so;   h[1] = so  - o[0]      + o[7];
    h[2] = st;   h[3] = st  - t[0]      + t[7];
    h[4] = soo;  h[5] = soo - o[0]*o[0] + o[7]*o[7];
    h[6] = stt;  h[7] = stt - t[0]*t[0] + t[7]*t[7];
    h[8] = sot;  h[9] = sot - o[0]*t[0] + o[7]*t[7];
}

__device__ __forceinline__ void ssim_nd(const float v[10], int px,
                                        float& num, float& den)
{
    const float m    = 1.0f / 49.0f;
    const float covn = 49.0f / 48.0f;
    const float C1   = 4.0e-4f;   // (0.01*2)^2
    const float C2   = 3.6e-3f;   // (0.03*2)^2
    float so  = v[0+px], st  = v[2+px];
    float soo = v[4+px], stt = v[6+px], sot = v[8+px];
    float ux  = so*m,  uy  = st*m;
    float uxx = soo*m, uyy = stt*m, uxy = sot*m;
    float vx  = covn*(uxx - ux*ux);
    float vy  = covn*(uyy - uy*uy);
    float vxy = covn*(uxy - ux*uy);
    float A1  = 2.0f*ux*uy + C1;
    float A2  = 2.0f*vxy + C2;
    float B1  = (ux*ux + uy*uy) + C1;
    float B2  = (vx + vy) + C2;
    num = A1*A2;
    den = B1*B2;
}

__global__ __launch_bounds__(NTHR, 3)
void ssim_main(const float* __restrict__ O, const float* __restrict__ T,
               float* __restrict__ accp)
{
    const int t  = threadIdx.x;
    const int c0 = blockIdx.x * CPB + 2*t;     // first of the 2 output cols
    const int r0 = blockIdx.y * ROWS;          // first output row of strip
    const int rows_in = min(ROWS, OH - r0);    // runtime to the compiler!
    const int hlim    = (H_IMG - 1) - r0;      // last in-bounds input row (rel)

    float acc = 0.0f;

    if (c0 < OW) {  // c0 even, OW even -> both pixels valid together
        const float* baseO = O + (size_t)r0 * W_IMG + c0;
        const float* baseT = T + (size_t)r0 * W_IMG + c0;

        float ring[7][10];   // 7-row delay line of horizontal sums (AGPRs)
        float v[10];         // running vertical sums over the 7-row window
        #pragma unroll
        for (int q = 0; q < 10; q++) v[q] = 0.0f;

        // warm-up: input rows 0..5 (one straight region; compiler pipelines)
        #pragma unroll
        for (int i = 0; i < 6; i++) {
            float co[8], ct[8], h[10];
            load8(baseO + (size_t)i * W_IMG, co);
            load8(baseT + (size_t)i * W_IMG, ct);
            hsums_reg(co, ct, h);
            #pragma unroll
            for (int q = 0; q < 10; q++) { v[q] += h[q]; ring[i][q] = h[q]; }
        }

        // prime the pipeline: prefetch input row 6 (first steady row)
        float po[8], pt[8];
        load8(baseO + (size_t)6 * W_IMG, po);
        load8(baseT + (size_t)6 * W_IMG, pt);

        // steady: output row j (input row i = j+6); chunked by 7 so ring
        // slot indices are compile-time constants. Guards stay RUNTIME.
        for (int jb = 0; jb < ROWS; jb += 7) {
            #pragma unroll
            for (int u = 0; u < 7; u++) {
                const int j = jb + u;
                if (j < rows_in) {
                    const int i = j + 6;
                    // consume prefetched pixels
                    float co[8], ct[8];
                    #pragma unroll
                    for (int q = 0; q < 8; q++) { co[q] = po[q]; ct[q] = pt[q]; }
                    // issue next row's loads NOW (hide under this row's math);
                    // clamp keeps the last strip's final prefetch in-bounds
                    // (value unused).
                    const int inext = min(i + 1, hlim);
                    load8(baseO + (size_t)inext * W_IMG, po);
                    load8(baseT + (size_t)inext * W_IMG, pt);

                    float h[10];
                    hsums_reg(co, ct, h);
                    #pragma unroll
                    for (int q = 0; q < 10; q++) v[q] += h[q];
                    // window now covers rows [j, j+6]
                    float n0, d0, n1, d1;
                    ssim_nd(v, 0, n0, d0);
                    ssim_nd(v, 1, n1, d1);
                    acc = fmaf(fmaf(n0, d1, n1*d0),
                               __builtin_amdgcn_rcpf(d0*d1), acc);
                    // drop row i-6 (slot u), store row i (slot (u+6)%7)
                    #pragma unroll
                    for (int q = 0; q < 10; q++) {
                        v[q] -= ring[u][q];
                        ring[(u + 6) % 7][q] = h[q];
                    }
                }
            }
        }
    }

    // wave(64) shuffle reduction
    #pragma unroll
    for (int off = 32; off; off >>= 1) acc += __shfl_down(acc, off);

    __shared__ float wpart[NTHR / 64];
    if ((t & 63) == 0) wpart[t >> 6] = acc;
    __syncthreads();
    if (t == 0) {
        float s = 0.0f;
        #pragma unroll
        for (int w = 0; w < NTHR / 64; w++) s += wpart[w];
        atomicAdd(accp, s);   // one atomic per block (3272 total)
    }
}

__global__ void ssim_final(const float* __restrict__ accp, float* __restrict__ out)
{
    out[0] = accp[0] * (float)(1.0 / ((double)OW * (double)OH));
}

extern "C" void kernel_launch(void* const* d_in, const int* in_sizes, int n_in,
                              void* d_out, int out_size, void* d_ws, size_t ws_size,
                              hipStream_t stream)
{
    const float* O = (const float*)d_in[0];
    const float* T = (const float*)d_in[1];
    float* out = (float*)d_out;
    float* acc = (float*)d_ws;

    hipMemsetAsync(acc, 0, sizeof(float), stream);   // ws is re-poisoned to 0xAA

    dim3 grid((OW + CPB - 1) / CPB, OH / ROWS);      // (8, 409)
    ssim_main<<<grid, NTHR, 0, stream>>>(O, T, acc);
    ssim_final<<<1, 1, 0, stream>>>(acc, out);
}

// Round 7
// 170.630 us; speedup vs baseline: 1.0345x; 1.0345x over previous
//
#include <hip/hip_runtime.h>

// SSIM (skimage default): 7x7 uniform filter, valid crop (pad=3), sample cov.
// Images: 4096x4096 fp32, output region 4090x4090, result = mean(S) scalar.
//
// R7: ping-pong depth-1 prefetch. R6's prefetch failed because the
// consume-copy (po->co) at iteration top put the vmcnt wait ~0 instructions
// after the loads AND added 16 movs/row (VALU 40->45us, stall only -3us).
// Here two register buffer sets alternate by COMPILE-TIME parity of j:
// iteration j issues row (j+7)'s loads into P[(j+1)&1], then consumes
// P[j&1] directly in hsums. Counted vmcnt waits let the next row's loads
// fly across the whole current row's compute.
//  - jb-loop manually unrolled into two chunks (jb=0: u=0..6, jb=7: u=0..2
//    live) so parity and ring slots are template constants. Runtime
//    `rows_in` guards KEPT (load-bearing codegen fences per R1/R2 spills;
//    always-true at ROWS=10 since 4090=409*10 -> zero real divergence).
//  - ROWS=10, float2 loads, single-rcp epilogue (all proven in R4-R6).
// History: R0 92us -> R4 74.5us (grid 3272) -> R5 107 (bad bundle, reverted)
// -> R6 76.5 (copy-defeated prefetch). Falsifier for R7: WRITE_SIZE>10MB or
// VGPR>120 -> spill, revert to R4 body.

#define W_IMG   4096
#define H_IMG   4096
#define OW      4090
#define OH      4090
#define ROWS    10            // output rows per block strip; divides 4090
#define NTHR    256           // threads per block
#define CPB     512           // output columns per block (2 per thread)

__device__ __forceinline__ void load8(const float* __restrict__ p, float o[8])
{
    // 8 consecutive floats, 8B-aligned (c0 even): 4x global_load_dwordx2
    float2 a0 = *(const float2*)(p + 0);
    float2 a1 = *(const float2*)(p + 2);
    float2 a2 = *(const float2*)(p + 4);
    float2 a3 = *(const float2*)(p + 6);
    o[0]=a0.x; o[1]=a0.y; o[2]=a1.x; o[3]=a1.y;
    o[4]=a2.x; o[5]=a2.y; o[6]=a3.x; o[7]=a3.y;
}

__device__ __forceinline__ void hsums_reg(const float o[8], const float t[8],
                                          float h[10])
{
    float so  = ((o[0]+o[1])+(o[2]+o[3])) + ((o[4]+o[5])+o[6]);
    float st  = ((t[0]+t[1])+(t[2]+t[3])) + ((t[4]+t[5])+t[6]);
    float soo = fmaf(o[6],o[6], fmaf(o[5],o[5], fmaf(o[4],o[4], fmaf(o[3],o[3], fmaf(o[2],o[2], fmaf(o[1],o[1], o[0]*o[0]))))));
    float stt = fmaf(t[6],t[6], fmaf(t[5],t[5], fmaf(t[4],t[4], fmaf(t[3],t[3], fmaf(t[2],t[2], fmaf(t[1],t[1], t[0]*t[0]))))));
    float sot = fmaf(o[6],t[6], fmaf(o[5],t[5], fmaf(o[4],t[4], fmaf(o[3],t[3], fmaf(o[2],t[2], fmaf(o[1],t[1], o[0]*t[0]))))));

    h[0] = so;   h[1] = so  - o[0]      + o[7];
    h[2] = st;   h[3] = st  - t[0]      + t[7];
    h[4] = soo;  h[5] = soo - o[0]*o[0] + o[7]*o[7];
    h[6] = stt;  h[7] = stt - t[0]*t[0] + t[7]*t[7];
    h[8] = sot;  h[9] = sot - o[0]*t[0] + o[7]*t[7];
}

__device__ __forceinline__ void ssim_nd(const float v[10], int px,
                                        float& num, float& den)
{
    const float m    = 1.0f / 49.0f;
    const float covn = 49.0f / 48.0f;
    const float C1   = 4.0e-4f;   // (0.01*2)^2
    const float C2   = 3.6e-3f;   // (0.03*2)^2
    float so  = v[0+px], st  = v[2+px];
    float soo = v[4+px], stt = v[6+px], sot = v[8+px];
    float ux  = so*m,  uy  = st*m;
    float uxx = soo*m, uyy = stt*m, uxy = sot*m;
    float vx  = covn*(uxx - ux*ux);
    float vy  = covn*(uyy - uy*uy);
    float vxy = covn*(uxy - ux*uy);
    float A1  = 2.0f*ux*uy + C1;
    float A2  = 2.0f*vxy + C2;
    float B1  = (ux*ux + uy*uy) + C1;
    float B2  = (vx + vy) + C2;
    num = A1*A2;
    den = B1*B2;
}

// One steady-state row. JB+U = output row j (compile-time), ring slot = U.
// cons_*: pixels of input row j+6 (prefetched last iteration).
// iss_* : destination for input row j+7's loads (issued here, waited next).
template<int JB, int U>
__device__ __forceinline__ void step(int rows_in, int hlim,
                                     const float* __restrict__ baseO,
                                     const float* __restrict__ baseT,
                                     float (&cons_o)[8], float (&cons_t)[8],
                                     float (&iss_o)[8],  float (&iss_t)[8],
                                     float (&ring)[7][10], float (&v)[10],
                                     float& acc)
{
    const int j = JB + U;
    if (j < rows_in) {              // runtime fence (always true at ROWS=10)
        const int i = j + 6;
        // issue NEXT row's loads first -> full row of compute before wait.
        // Clamp keeps the last strip's final prefetch in-bounds (unused).
        const int inext = min(i + 1, hlim);
        load8(baseO + (size_t)inext * W_IMG, iss_o);
        load8(baseT + (size_t)inext * W_IMG, iss_t);

        float h[10];
        hsums_reg(cons_o, cons_t, h);     // waits on cons_* loads here
        #pragma unroll
        for (int q = 0; q < 10; q++) v[q] += h[q];
        // window now covers rows [j, j+6]
        float n0, d0, n1, d1;
        ssim_nd(v, 0, n0, d0);
        ssim_nd(v, 1, n1, d1);
        acc = fmaf(fmaf(n0, d1, n1*d0), __builtin_amdgcn_rcpf(d0*d1), acc);
        // drop row i-6 (slot U), store row i (slot (U+6)%7)
        #pragma unroll
        for (int q = 0; q < 10; q++) {
            v[q] -= ring[U][q];
            ring[(U + 6) % 7][q] = h[q];
        }
    }
}

__global__ __launch_bounds__(NTHR, 3)
void ssim_main(const float* __restrict__ O, const float* __restrict__ T,
               float* __restrict__ accp)
{
    const int t  = threadIdx.x;
    const int c0 = blockIdx.x * CPB + 2*t;     // first of the 2 output cols
    const int r0 = blockIdx.y * ROWS;          // first output row of strip
    const int rows_in = min(ROWS, OH - r0);    // runtime to the compiler!
    const int hlim    = (H_IMG - 1) - r0;      // last in-bounds input row (rel)

    float acc = 0.0f;

    if (c0 < OW) {  // c0 even, OW even -> both pixels valid together
        const float* baseO = O + (size_t)r0 * W_IMG + c0;
        const float* baseT = T + (size_t)r0 * W_IMG + c0;

        float ring[7][10];   // 7-row delay line of horizontal sums (AGPRs)
        float v[10];         // running vertical sums over the 7-row window
        #pragma unroll
        for (int q = 0; q < 10; q++) v[q] = 0.0f;

        // warm-up: input rows 0..5
        #pragma unroll
        for (int i = 0; i < 6; i++) {
            float co[8], ct[8], h[10];
            load8(baseO + (size_t)i * W_IMG, co);
            load8(baseT + (size_t)i * W_IMG, ct);
            hsums_reg(co, ct, h);
            #pragma unroll
            for (int q = 0; q < 10; q++) { v[q] += h[q]; ring[i][q] = h[q]; }
        }

        // ping-pong buffers; prime A with input row 6 (first steady row)
        float pao[8], pat[8], pbo[8], pbt[8];
        load8(baseO + (size_t)6 * W_IMG, pao);
        load8(baseT + (size_t)6 * W_IMG, pat);

        // chunk jb=0: j = 0..6.  j even -> consume A, issue B; odd -> B, A.
        step<0,0>(rows_in, hlim, baseO, baseT, pao, pat, pbo, pbt, ring, v, acc);
        step<0,1>(rows_in, hlim, baseO, baseT, pbo, pbt, pao, pat, ring, v, acc);
        step<0,2>(rows_in, hlim, baseO, baseT, pao, pat, pbo, pbt, ring, v, acc);
        step<0,3>(rows_in, hlim, baseO, baseT, pbo, pbt, pao, pat, ring, v, acc);
        step<0,4>(rows_in, hlim, baseO, baseT, pao, pat, pbo, pbt, ring, v, acc);
        step<0,5>(rows_in, hlim, baseO, baseT, pbo, pbt, pao, pat, ring, v, acc);
        step<0,6>(rows_in, hlim, baseO, baseT, pao, pat, pbo, pbt, ring, v, acc);

        // chunk jb=7: j = 7..9 (u=3..6 guarded off).  j odd at u=0.
        step<7,0>(rows_in, hlim, baseO, baseT, pbo, pbt, pao, pat, ring, v, acc);
        step<7,1>(rows_in, hlim, baseO, baseT, pao, pat, pbo, pbt, ring, v, acc);
        step<7,2>(rows_in, hlim, baseO, baseT, pbo, pbt, pao, pat, ring, v, acc);
        step<7,3>(rows_in, hlim, baseO, baseT, pao, pat, pbo, pbt, ring, v, acc);
        step<7,4>(rows_in, hlim, baseO, baseT, pbo, pbt, pao, pat, ring, v, acc);
        step<7,5>(rows_in, hlim, baseO, baseT, pao, pat, pbo, pbt, ring, v, acc);
        step<7,6>(rows_in, hlim, baseO, baseT, pbo, pbt, pao, pat, ring, v, acc);
    }

    // wave(64) shuffle reduction
    #pragma unroll
    for (int off = 32; off; off >>= 1) acc += __shfl_down(acc, off);

    __shared__ float wpart[NTHR / 64];
    if ((t & 63) == 0) wpart[t >> 6] = acc;
    __syncthreads();
    if (t == 0) {
        float s = 0.0f;
        #pragma unroll
        for (int w = 0; w < NTHR / 64; w++) s += wpart[w];
        atomicAdd(accp, s);   // one atomic per block (3272 total)
    }
}

__global__ void ssim_final(const float* __restrict__ accp, float* __restrict__ out)
{
    out[0] = accp[0] * (float)(1.0 / ((double)OW * (double)OH));
}

extern "C" void kernel_launch(void* const* d_in, const int* in_sizes, int n_in,
                              void* d_out, int out_size, void* d_ws, size_t ws_size,
                              hipStream_t stream)
{
    const float* O = (const float*)d_in[0];
    const float* T = (const float*)d_in[1];
    float* out = (float*)d_out;
    float* acc = (float*)d_ws;

    hipMemsetAsync(acc, 0, sizeof(float), stream);   // ws is re-poisoned to 0xAA

    dim3 grid((OW + CPB - 1) / CPB, OH / ROWS);      // (8, 409)
    ssim_main<<<grid, NTHR, 0, stream>>>(O, T, acc);
    ssim_final<<<1, 1, 0, stream>>>(acc, out);
}

// Round 8
// 167.850 us; speedup vs baseline: 1.0516x; 1.0166x over previous
//
#include <hip/hip_runtime.h>

// SSIM (skimage default): 7x7 uniform filter, valid crop (pad=3), sample cov.
// Images: 4096x4096 fp32, output region 4090x4090, result = mean(S) scalar.
//
// R8 = R4 skeleton + two independent levers:
//  1. PAIR-ROW guarded regions. Hard-won codegen rules from R1-R7:
//     - runtime `rows_in` guards are load-bearing fences (no guard -> ring
//       spills 0.4-1.2GB, R1/R2);
//     - loads must be CONSUMED in the same guarded region they are ISSUED in
//       (cross-block prefetch gets vmcnt-drained at CF joins: R6 +2us,
//       R7 +18us stall).
//     => widen the region to 2 rows: issue both rows' 16 float2 loads at
//     region top; row j0's compute (~260cy) covers row j1's latency via
//     counted vmcnt. Exposed-latency events per row halve. 4090=409*10 so
//     the pair guard j1<rows_in is always-true (pure fence, no tail case).
//  2. Scaled epilogue: A1,B1 scaled by 49^2; A2,B2 by 48*49 (S invariant):
//     A1'=2*so*st+0.9604, B1'=so^2+st^2+0.9604,
//     A2'=98*sot-2*so*st+8.4672, B2'=49*(soo+stt)-(so^2+st^2)+8.4672.
//     11 ops/pixel vs ~20 (drops the 1/49 means and covn muls entirely).
// History: R0 92us -> R4 74.5 (ROWS=10 grid) -> R5 107 (bad bundle) ->
// R6 76.5 / R7 92 (cross-block prefetch defeated by CF waitcnt drain).
// Falsifier: WRITE_SIZE>10MB or VGPR>120 -> pairing spilled, revert it.

#define W_IMG   4096
#define H_IMG   4096
#define OW      4090
#define OH      4090
#define ROWS    10            // output rows per block strip; divides 4090
#define NTHR    256           // threads per block
#define CPB     512           // output columns per block (2 per thread)

__device__ __forceinline__ void load8(const float* __restrict__ p, float o[8])
{
    // 8 consecutive floats, 8B-aligned (c0 even): 4x global_load_dwordx2
    float2 a0 = *(const float2*)(p + 0);
    float2 a1 = *(const float2*)(p + 2);
    float2 a2 = *(const float2*)(p + 4);
    float2 a3 = *(const float2*)(p + 6);
    o[0]=a0.x; o[1]=a0.y; o[2]=a1.x; o[3]=a1.y;
    o[4]=a2.x; o[5]=a2.y; o[6]=a3.x; o[7]=a3.y;
}

__device__ __forceinline__ void hsums_reg(const float o[8], const float t[8],
                                          float h[10])
{
    float so  = ((o[0]+o[1])+(o[2]+o[3])) + ((o[4]+o[5])+o[6]);
    float st  = ((t[0]+t[1])+(t[2]+t[3])) + ((t[4]+t[5])+t[6]);
    float soo = fmaf(o[6],o[6], fmaf(o[5],o[5], fmaf(o[4],o[4], fmaf(o[3],o[3], fmaf(o[2],o[2], fmaf(o[1],o[1], o[0]*o[0]))))));
    float stt = fmaf(t[6],t[6], fmaf(t[5],t[5], fmaf(t[4],t[4], fmaf(t[3],t[3], fmaf(t[2],t[2], fmaf(t[1],t[1], t[0]*t[0]))))));
    float sot = fmaf(o[6],t[6], fmaf(o[5],t[5], fmaf(o[4],t[4], fmaf(o[3],t[3], fmaf(o[2],t[2], fmaf(o[1],t[1], o[0]*t[0]))))));

    h[0] = so;   h[1] = so  - o[0]      + o[7];
    h[2] = st;   h[3] = st  - t[0]      + t[7];
    h[4] = soo;  h[5] = soo - o[0]*o[0] + o[7]*o[7];
    h[6] = stt;  h[7] = stt - t[0]*t[0] + t[7]*t[7];
    h[8] = sot;  h[9] = sot - o[0]*t[0] + o[7]*t[7];
}

// Scaled SSIM numerator/denominator. Exact ratio-preserving rescale:
//   A1,B1 *= 49^2 ; A2,B2 *= 48*49.  K1=C1*2401, K2=C2*2352.
__device__ __forceinline__ void ssim_nd(const float v[10], int px,
                                        float& num, float& den)
{
    const float K1 = 0.9604f;     // 4.0e-4 * 2401
    const float K2 = 8.4672f;     // 3.6e-3 * 2352
    float so  = v[0+px], st  = v[2+px];
    float soo = v[4+px], stt = v[6+px], sot = v[8+px];
    float t1 = so*st;
    float A1 = fmaf(2.0f, t1, K1);
    float ss = fmaf(st, st, so*so);               // so^2+st^2
    float B1 = ss + K1;
    float A2 = fmaf(98.0f, sot, fmaf(-2.0f, t1, K2));
    float B2 = fmaf(49.0f, soo + stt, K2 - ss);
    num = A1*A2;
    den = B1*B2;
}

// One output row's accumulate/epilogue/ring rotation. J compile-time.
template<int J>
__device__ __forceinline__ void row_tail(const float (&h)[10],
                                         float (&ring)[7][10], float (&v)[10],
                                         float& n, float& d)
{
    #pragma unroll
    for (int q = 0; q < 10; q++) v[q] += h[q];
    ssim_nd(v, 0, n, d);
    float n1, d1;
    ssim_nd(v, 1, n1, d1);
    // fold pixel pair: n/d + n1/d1 = (n*d1 + n1*d)/(d*d1)
    n = fmaf(n, d1, n1*d);
    d = d*d1;
    #pragma unroll
    for (int q = 0; q < 10; q++) {
        v[q] -= ring[J % 7][q];                   // drop input row J-1's h
        ring[(J + 6) % 7][q] = h[q];              // store input row J+6's h
    }
}

// One guarded PAIR region: rows j0=2P, j1=2P+1. All loads issued at top,
// all consumed before region end (codegen rule: no cross-region liveness).
template<int P>
__device__ __forceinline__ void pair_step(int rows_in,
                                          const float* __restrict__ baseO,
                                          const float* __restrict__ baseT,
                                          float (&ring)[7][10], float (&v)[10],
                                          float& acc)
{
    constexpr int j0 = 2*P,   j1 = 2*P + 1;
    constexpr int i0 = j0+6,  i1 = j1 + 6;
    if (j1 < rows_in) {    // runtime fence; always true (OH%ROWS==0)
        float ao[8], at[8], bo[8], bt[8];
        load8(baseO + (size_t)i0 * W_IMG, ao);
        load8(baseT + (size_t)i0 * W_IMG, at);
        load8(baseO + (size_t)i1 * W_IMG, bo);   // in flight across row j0
        load8(baseT + (size_t)i1 * W_IMG, bt);

        float h[10], n0, d0;
        hsums_reg(ao, at, h);                    // waits vmcnt(16 outstanding->8)
        row_tail<j0>(h, ring, v, n0, d0);

        float h2[10], n1, d1;
        hsums_reg(bo, bt, h2);                   // latency hidden by row j0
        row_tail<j1>(h2, ring, v, n1, d1);

        // one quarter-rate rcp per pair (2 rows x 2 pixels)
        acc = fmaf(fmaf(n0, d1, n1*d0), __builtin_amdgcn_rcpf(d0*d1), acc);
    }
}

__global__ __launch_bounds__(NTHR, 3)
void ssim_main(const float* __restrict__ O, const float* __restrict__ T,
               float* __restrict__ accp)
{
    const int t  = threadIdx.x;
    const int c0 = blockIdx.x * CPB + 2*t;     // first of the 2 output cols
    const int r0 = blockIdx.y * ROWS;          // first output row of strip
    const int rows_in = min(ROWS, OH - r0);    // runtime to the compiler!

    float acc = 0.0f;

    if (c0 < OW) {  // c0 even, OW even -> both pixels valid together
        const float* baseO = O + (size_t)r0 * W_IMG + c0;
        const float* baseT = T + (size_t)r0 * W_IMG + c0;

        float ring[7][10];   // 7-row delay line of horizontal sums (AGPRs)
        float v[10];         // running vertical sums over the 7-row window
        #pragma unroll
        for (int q = 0; q < 10; q++) v[q] = 0.0f;

        // warm-up: input rows 0..5 (identical to R4)
        #pragma unroll
        for (int i = 0; i < 6; i++) {
            float co[8], ct[8], h[10];
            load8(baseO + (size_t)i * W_IMG, co);
            load8(baseT + (size_t)i * W_IMG, ct);
            hsums_reg(co, ct, h);
            #pragma unroll
            for (int q = 0; q < 10; q++) { v[q] += h[q]; ring[i][q] = h[q]; }
        }

        // steady: 5 pair regions cover output rows 0..9
        pair_step<0>(rows_in, baseO, baseT, ring, v, acc);
        pair_step<1>(rows_in, baseO, baseT, ring, v, acc);
        pair_step<2>(rows_in, baseO, baseT, ring, v, acc);
        pair_step<3>(rows_in, baseO, baseT, ring, v, acc);
        pair_step<4>(rows_in, baseO, baseT, ring, v, acc);
    }

    // wave(64) shuffle reduction
    #pragma unroll
    for (int off = 32; off; off >>= 1) acc += __shfl_down(acc, off);

    __shared__ float wpart[NTHR / 64];
    if ((t & 63) == 0) wpart[t >> 6] = acc;
    __syncthreads();
    if (t == 0) {
        float s = 0.0f;
        #pragma unroll
        for (int w = 0; w < NTHR / 64; w++) s += wpart[w];
        atomicAdd(accp, s);   // one atomic per block (3272 total)
    }
}

__global__ void ssim_final(const float* __restrict__ accp, float* __restrict__ out)
{
    out[0] = accp[0] * (float)(1.0 / ((double)OW * (double)OH));
}

extern "C" void kernel_launch(void* const* d_in, const int* in_sizes, int n_in,
                              void* d_out, int out_size, void* d_ws, size_t ws_size,
                              hipStream_t stream)
{
    const float* O = (const float*)d_in[0];
    const float* T = (const float*)d_in[1];
    float* out = (float*)d_out;
    float* acc = (float*)d_ws;

    hipMemsetAsync(acc, 0, sizeof(float), stream);   // ws is re-poisoned to 0xAA

    dim3 grid((OW + CPB - 1) / CPB, OH / ROWS);      // (8, 409)
    ssim_main<<<grid, NTHR, 0, stream>>>(O, T, acc);
    ssim_final<<<1, 1, 0, stream>>>(acc, out);
}